// Round 2
// baseline (1703.890 us; speedup 1.0000x reference)
//
#include <hip/hip_runtime.h>
#include <math.h>

// ============================================================================
// HypersphereBlock (nGPT-style transformer block), MI355X / gfx950.
// I/O dtype: fp32 (per reference). Internal compute: bf16 MFMA, fp32 accum.
// B=2 S=2048 D=2048 H=16 hd=128 F=8192.
// ws layout (bytes): bf16 weights 100.7M | h fp32 33.5M | qb 16.8M |
//   [xb|kb|vb + 16.7M tail, reused as mid 67.1M]  => 218.1 MB total.
// ============================================================================

typedef unsigned short ushort_t;
typedef __attribute__((ext_vector_type(8))) short short8;
typedef __attribute__((ext_vector_type(4))) short short4v;
typedef __attribute__((ext_vector_type(4))) float f32x4;

#define S_LEN 2048
#define D_DIM 2048
#define F_DIM 8192
#define NHEAD 16
#define HDIM 128
#define BATCH 2
#define MROWS (BATCH * S_LEN)

__device__ __forceinline__ float bf2f(ushort_t u) {
  union { unsigned int i; float f; } c; c.i = ((unsigned int)u) << 16; return c.f;
}
__device__ __forceinline__ ushort_t f2bf(float f) {
  union { unsigned int i; float f; } c; c.f = f;
  unsigned int u = c.i;
  unsigned int r = (u + 0x7FFFu + ((u >> 16) & 1u)) >> 16;  // RNE
  return (ushort_t)r;
}
__device__ __forceinline__ void load_lds16(const ushort_t* g, ushort_t* l) {
  __builtin_amdgcn_global_load_lds((const __attribute__((address_space(1))) void*)g,
                                   (__attribute__((address_space(3))) void*)l,
                                   16, 0, 0);
}

// ---------------------------------------------------------------------------
// fp32 -> bf16 conversion (weights). 4 elems/thread.
// ---------------------------------------------------------------------------
__global__ __launch_bounds__(256) void f2b_kernel(const float* __restrict__ in,
                                                  ushort_t* __restrict__ out) {
  const size_t i = ((size_t)blockIdx.x * 256 + threadIdx.x) * 4;
  float4 v = *(const float4*)(in + i);
  short4v o;
  o[0] = (short)f2bf(v.x); o[1] = (short)f2bf(v.y);
  o[2] = (short)f2bf(v.z); o[3] = (short)f2bf(v.w);
  *(short4v*)(out + i) = o;
}

// ---------------------------------------------------------------------------
// hypersphere norm: out_bf16 = x/(||x||+eps) * sqrt(D) * g.  One block/row.
// ---------------------------------------------------------------------------
__global__ __launch_bounds__(256) void hsnorm_kernel(const float* __restrict__ x,
                                                     const float* __restrict__ g,
                                                     ushort_t* __restrict__ out) {
  const int row = blockIdx.x;
  const int t = threadIdx.x;
  const size_t base = (size_t)row * D_DIM + t * 8;
  float4 x0 = *(const float4*)(x + base);
  float4 x1 = *(const float4*)(x + base + 4);
  float f[8] = {x0.x, x0.y, x0.z, x0.w, x1.x, x1.y, x1.z, x1.w};
  float ss = 0.f;
#pragma unroll
  for (int j = 0; j < 8; ++j) ss += f[j] * f[j];
#pragma unroll
  for (int o = 32; o >= 1; o >>= 1) ss += __shfl_xor(ss, o);
  __shared__ float red[4];
  if ((t & 63) == 0) red[t >> 6] = ss;
  __syncthreads();
  const float tot = red[0] + red[1] + red[2] + red[3];
  const float factor = 45.254833995939045f / (sqrtf(tot) + 1e-6f);  // sqrt(2048)
  float4 g0 = *(const float4*)(g + t * 8);
  float4 g1 = *(const float4*)(g + t * 8 + 4);
  float gg[8] = {g0.x, g0.y, g0.z, g0.w, g1.x, g1.y, g1.z, g1.w};
  short8 ov;
#pragma unroll
  for (int j = 0; j < 8; ++j) ov[j] = (short)f2bf(f[j] * factor * gg[j]);
  *(short8*)(out + base) = ov;
}

// ---------------------------------------------------------------------------
// QK-norm (bf16 in-place): each 128-elem head vector -> unit norm * scale.
// One wave per vector; qk_norm_factor folded into q's scale.
// ---------------------------------------------------------------------------
__global__ __launch_bounds__(256) void qknorm_kernel(ushort_t* __restrict__ buf, float scale) {
  const int wv = threadIdx.x >> 6;
  const int lane = threadIdx.x & 63;
  const size_t vi = (size_t)blockIdx.x * 4 + wv;
  ushort_t* p = buf + vi * 128 + lane * 2;
  const float a = bf2f(p[0]), b = bf2f(p[1]);
  float ss = a * a + b * b;
#pragma unroll
  for (int o = 32; o >= 1; o >>= 1) ss += __shfl_xor(ss, o);
  const float f = scale / (sqrtf(ss) + 1e-6f);
  p[0] = f2bf(a * f);
  p[1] = f2bf(b * f);
}

// ---------------------------------------------------------------------------
// GEMM: C[M,N] = epi(A[M,K]_bf16 · W[N,K]_bf16^T (+ RES_fp32)).
// 128x128 tile, BK=32, 4 waves (2x2), each wave 4x4 MFMA 16x16x32_bf16.
// global_load_lds width=16 staging (m97 structure).
// EPI: 0 = store bf16; 1 = +RES fp32, store fp32; 2 = exact GELU, store bf16.
// ---------------------------------------------------------------------------
template <int EPI>
__global__ __launch_bounds__(256) void gemm_bt(const ushort_t* __restrict__ A,
                                               const ushort_t* __restrict__ W,
                                               const float* __restrict__ RES,
                                               void* __restrict__ Cv,
                                               int M, int N, int K) {
  __shared__ __align__(16) ushort_t a_lds[128 * 32];
  __shared__ __align__(16) ushort_t b_lds[128 * 32];
  const int tid = threadIdx.x;
  const int w = tid >> 6;
  const int lane = tid & 63;
  const int quad = lane >> 4;
  const int l15 = lane & 15;
  const int wr = w >> 1, wc = w & 1;
  const long bm = (long)blockIdx.y * 128;
  const long bn = (long)blockIdx.x * 128;

  const int srow = tid >> 2;
  const int scol = (tid & 3) * 8;
  const ushort_t* gA = A + (size_t)(bm + srow) * K + scol;
  const ushort_t* gB = W + (size_t)(bn + srow) * K + scol;
  ushort_t* lA = a_lds + w * 512;  // wave-uniform base; HW scatters lane*16B
  ushort_t* lB = b_lds + w * 512;
  const size_t half = (size_t)64 * K;

  f32x4 acc[4][4] = {};

  for (int k0 = 0; k0 < K; k0 += 32) {
    load_lds16(gA, lA);
    load_lds16(gA + half, lA + 2048);
    load_lds16(gB, lB);
    load_lds16(gB + half, lB + 2048);
    gA += 32; gB += 32;
    __syncthreads();
    short8 af[4], bfr[4];
#pragma unroll
    for (int i = 0; i < 4; ++i) {
      af[i]  = *(const short8*)&a_lds[(wr * 64 + i * 16 + l15) * 32 + quad * 8];
      bfr[i] = *(const short8*)&b_lds[(wc * 64 + i * 16 + l15) * 32 + quad * 8];
    }
#pragma unroll
    for (int i = 0; i < 4; ++i)
#pragma unroll
      for (int j = 0; j < 4; ++j)
        acc[i][j] = __builtin_amdgcn_mfma_f32_16x16x32_bf16(af[i], bfr[j], acc[i][j], 0, 0, 0);
    __syncthreads();
  }

#pragma unroll
  for (int i = 0; i < 4; ++i) {
    const long row0 = bm + wr * 64 + i * 16 + quad * 4;
#pragma unroll
    for (int j = 0; j < 4; ++j) {
      const long col = bn + wc * 64 + j * 16 + l15;
#pragma unroll
      for (int r = 0; r < 4; ++r) {
        float v = acc[i][j][r];
        const size_t idx = (size_t)(row0 + r) * N + col;
        if (EPI == 1) {
          ((float*)Cv)[idx] = v + RES[idx];
        } else if (EPI == 2) {
          v = 0.5f * v * (1.0f + erff(v * 0.70710678118654752f));
          ((ushort_t*)Cv)[idx] = f2bf(v);
        } else {
          ((ushort_t*)Cv)[idx] = f2bf(v);
        }
      }
    }
  }
}

// ---------------------------------------------------------------------------
// Causal flash attention (all bf16). One wave per (b,h,16-row Q-tile).
// K-tiles of 32. QK^T via MFMA; online softmax (quad shfl reductions);
// P routes C-layout -> LDS -> A-layout; V staged transposed in LDS.
// q pre-normalized AND pre-scaled by qk_norm_factor; k pre-normalized.
// ---------------------------------------------------------------------------
__global__ __launch_bounds__(64) void attn_kernel(const ushort_t* __restrict__ q,
                                                  const ushort_t* __restrict__ k,
                                                  const ushort_t* __restrict__ v,
                                                  ushort_t* __restrict__ out) {
  __shared__ __align__(16) ushort_t V_lds[HDIM * 32];  // [d][key]
  __shared__ __align__(16) ushort_t P_lds[16 * 32];    // [q][key]
  const int lane = threadIdx.x;
  const int quad = lane >> 4;
  const int l15 = lane & 15;
  const int qt = blockIdx.x & (S_LEN / 16 - 1);
  const int bh = blockIdx.x >> 7;
  const int b = bh >> 4;
  const int h = bh & 15;
  const int q0 = qt * 16;
  const size_t base = ((size_t)b * S_LEN) * D_DIM + h * HDIM;

  short8 qa[4];
#pragma unroll
  for (int st = 0; st < 4; ++st)
    qa[st] = *(const short8*)(q + base + (size_t)(q0 + l15) * D_DIM + st * 32 + quad * 8);

  f32x4 o[8] = {};
  float m[4], l[4];
#pragma unroll
  for (int r = 0; r < 4; ++r) { m[r] = -__builtin_inff(); l[r] = 0.f; }

  const int ktmax = (q0 + 15) >> 5;
  for (int kt = 0; kt <= ktmax; ++kt) {
#pragma unroll
    for (int t = 0; t < 8; ++t) {
      const int flat = t * 512 + lane * 8;
      const int key = flat >> 7;
      const int d = flat & 127;
      short8 vv = *(const short8*)(v + base + (size_t)(kt * 32 + key) * D_DIM + d);
#pragma unroll
      for (int j = 0; j < 8; ++j) V_lds[(d + j) * 32 + key] = (ushort_t)vv[j];
    }

    f32x4 s[2];
#pragma unroll
    for (int h2 = 0; h2 < 2; ++h2) {
      f32x4 sa = {};
#pragma unroll
      for (int st = 0; st < 4; ++st) {
        short8 kb = *(const short8*)(k + base + (size_t)(kt * 32 + h2 * 16 + l15) * D_DIM + st * 32 + quad * 8);
        sa = __builtin_amdgcn_mfma_f32_16x16x32_bf16(qa[st], kb, sa, 0, 0, 0);
      }
      s[h2] = sa;
    }

    const int key_lo = kt * 32 + l15;
    const int key_hi = key_lo + 16;
    float alpha[4];
#pragma unroll
    for (int r = 0; r < 4; ++r) {
      const int qrow = q0 + quad * 4 + r;
      float s0 = (key_lo <= qrow) ? s[0][r] : -__builtin_inff();
      float s1 = (key_hi <= qrow) ? s[1][r] : -__builtin_inff();
      float tmax = fmaxf(s0, s1);
#pragma unroll
      for (int off = 8; off >= 1; off >>= 1) tmax = fmaxf(tmax, __shfl_xor(tmax, off));
      const float mn = fmaxf(m[r], tmax);
      const float al = __expf(m[r] - mn);
      const float p0 = __expf(s0 - mn);
      const float p1 = __expf(s1 - mn);
      float ps = p0 + p1;
#pragma unroll
      for (int off = 8; off >= 1; off >>= 1) ps += __shfl_xor(ps, off);
      l[r] = l[r] * al + ps;
      m[r] = mn;
      alpha[r] = al;
      P_lds[(quad * 4 + r) * 32 + l15] = f2bf(p0);
      P_lds[(quad * 4 + r) * 32 + l15 + 16] = f2bf(p1);
    }

    __syncthreads();

#pragma unroll
    for (int c = 0; c < 8; ++c)
#pragma unroll
      for (int r = 0; r < 4; ++r) o[c][r] *= alpha[r];

    short8 af = *(const short8*)&P_lds[l15 * 32 + quad * 8];
#pragma unroll
    for (int c = 0; c < 8; ++c) {
      short8 vb = *(const short8*)&V_lds[(c * 16 + l15) * 32 + quad * 8];
      o[c] = __builtin_amdgcn_mfma_f32_16x16x32_bf16(af, vb, o[c], 0, 0, 0);
    }
    __syncthreads();
  }

#pragma unroll
  for (int c = 0; c < 8; ++c)
#pragma unroll
    for (int r = 0; r < 4; ++r) {
      const float val = o[c][r] / l[r];
      out[base + (size_t)(q0 + quad * 4 + r) * D_DIM + c * 16 + l15] = f2bf(val);
    }
}

// ---------------------------------------------------------------------------
extern "C" void kernel_launch(void* const* d_in, const int* in_sizes, int n_in,
                              void* d_out, int out_size, void* d_ws, size_t ws_size,
                              hipStream_t stream) {
  const float* hid  = (const float*)d_in[0];
  const float* Wq   = (const float*)d_in[1];
  const float* Wk   = (const float*)d_in[2];
  const float* Wv   = (const float*)d_in[3];
  const float* Wo   = (const float*)d_in[4];
  const float* Win  = (const float*)d_in[5];
  const float* Wout = (const float*)d_in[6];
  // d_in[7] = qk_norm_factor == 1/sqrt(128), folded in as exact constant.
  const float* ga   = (const float*)d_in[8];
  const float* gm   = (const float*)d_in[9];
  float* out = (float*)d_out;

  const size_t DD = (size_t)D_DIM * D_DIM;    // 4,194,304
  const size_t FD = (size_t)F_DIM * D_DIM;    // 16,777,216
  const size_t SZ = (size_t)MROWS * D_DIM;    // 8,388,608

  ushort_t* wqb  = (ushort_t*)d_ws;
  ushort_t* wkb  = wqb + DD;
  ushort_t* wvb  = wkb + DD;
  ushort_t* wob  = wvb + DD;
  ushort_t* winb = wob + DD;
  ushort_t* woutb= winb + FD;
  float*    hb   = (float*)(woutb + FD);      // h = hid + attn@Wo^T (fp32)
  ushort_t* qb   = (ushort_t*)(hb + SZ);      // q, later y_norm
  ushort_t* xb   = qb + SZ;                   // x_norm, later attn-out
  ushort_t* kb   = xb + SZ;
  ushort_t* vb   = kb + SZ;
  ushort_t* mid  = xb;                        // 4096x8192 bf16, overlays xb/kb/vb + tail

  const dim3 gD(D_DIM / 128, MROWS / 128);
  const dim3 gF(F_DIM / 128, MROWS / 128);

  // weight conversion fp32 -> bf16
  f2b_kernel<<<DD / 1024, 256, 0, stream>>>(Wq, wqb);
  f2b_kernel<<<DD / 1024, 256, 0, stream>>>(Wk, wkb);
  f2b_kernel<<<DD / 1024, 256, 0, stream>>>(Wv, wvb);
  f2b_kernel<<<DD / 1024, 256, 0, stream>>>(Wo, wob);
  f2b_kernel<<<FD / 1024, 256, 0, stream>>>(Win, winb);
  f2b_kernel<<<FD / 1024, 256, 0, stream>>>(Wout, woutb);

  hsnorm_kernel<<<MROWS, 256, 0, stream>>>(hid, ga, xb);
  gemm_bt<0><<<gD, 256, 0, stream>>>(xb, wqb, nullptr, qb, MROWS, D_DIM, D_DIM);
  gemm_bt<0><<<gD, 256, 0, stream>>>(xb, wkb, nullptr, kb, MROWS, D_DIM, D_DIM);
  gemm_bt<0><<<gD, 256, 0, stream>>>(xb, wvb, nullptr, vb, MROWS, D_DIM, D_DIM);
  qknorm_kernel<<<(MROWS * NHEAD) / 4, 256, 0, stream>>>(qb, 0.08838834764831845f);
  qknorm_kernel<<<(MROWS * NHEAD) / 4, 256, 0, stream>>>(kb, 1.0f);
  attn_kernel<<<BATCH * NHEAD * (S_LEN / 16), 64, 0, stream>>>(qb, kb, vb, xb);
  gemm_bt<1><<<gD, 256, 0, stream>>>(xb, wob, hid, hb, MROWS, D_DIM, D_DIM);
  hsnorm_kernel<<<MROWS, 256, 0, stream>>>(hb, gm, qb);
  gemm_bt<2><<<gF, 256, 0, stream>>>(qb, winb, nullptr, mid, MROWS, F_DIM, D_DIM);
  gemm_bt<1><<<gD, 256, 0, stream>>>(mid, woutb, hb, out, MROWS, D_DIM, F_DIM);
}

// Round 3
// 1188.854 us; speedup vs baseline: 1.4332x; 1.4332x over previous
//
#include <hip/hip_runtime.h>
#include <math.h>

// ============================================================================
// HypersphereBlock (nGPT-style transformer block), MI355X / gfx950.
// I/O dtype: fp32. Internal compute: bf16 MFMA, fp32 accum.
// B=2 S=2048 D=2048 H=16 hd=128 F=8192.
// R3: attention rewritten — 4-wave blocks, 64-row Q tiles, K/V^T staged in
// LDS via global_load_lds, V transposed in the V-GEMM epilogue (EPI=3).
// ============================================================================

typedef unsigned short ushort_t;
typedef __attribute__((ext_vector_type(8))) short short8;
typedef __attribute__((ext_vector_type(4))) short short4v;
typedef __attribute__((ext_vector_type(4))) float f32x4;

#define S_LEN 2048
#define D_DIM 2048
#define F_DIM 8192
#define NHEAD 16
#define HDIM 128
#define BATCH 2
#define MROWS (BATCH * S_LEN)

__device__ __forceinline__ float bf2f(ushort_t u) {
  union { unsigned int i; float f; } c; c.i = ((unsigned int)u) << 16; return c.f;
}
__device__ __forceinline__ ushort_t f2bf(float f) {
  union { unsigned int i; float f; } c; c.f = f;
  unsigned int u = c.i;
  unsigned int r = (u + 0x7FFFu + ((u >> 16) & 1u)) >> 16;  // RNE
  return (ushort_t)r;
}
__device__ __forceinline__ void load_lds16(const ushort_t* g, ushort_t* l) {
  __builtin_amdgcn_global_load_lds((const __attribute__((address_space(1))) void*)g,
                                   (__attribute__((address_space(3))) void*)l,
                                   16, 0, 0);
}

// ---------------------------------------------------------------------------
__global__ __launch_bounds__(256) void f2b_kernel(const float* __restrict__ in,
                                                  ushort_t* __restrict__ out) {
  const size_t i = ((size_t)blockIdx.x * 256 + threadIdx.x) * 4;
  float4 v = *(const float4*)(in + i);
  short4v o;
  o[0] = (short)f2bf(v.x); o[1] = (short)f2bf(v.y);
  o[2] = (short)f2bf(v.z); o[3] = (short)f2bf(v.w);
  *(short4v*)(out + i) = o;
}

// ---------------------------------------------------------------------------
__global__ __launch_bounds__(256) void hsnorm_kernel(const float* __restrict__ x,
                                                     const float* __restrict__ g,
                                                     ushort_t* __restrict__ out) {
  const int row = blockIdx.x;
  const int t = threadIdx.x;
  const size_t base = (size_t)row * D_DIM + t * 8;
  float4 x0 = *(const float4*)(x + base);
  float4 x1 = *(const float4*)(x + base + 4);
  float f[8] = {x0.x, x0.y, x0.z, x0.w, x1.x, x1.y, x1.z, x1.w};
  float ss = 0.f;
#pragma unroll
  for (int j = 0; j < 8; ++j) ss += f[j] * f[j];
#pragma unroll
  for (int o = 32; o >= 1; o >>= 1) ss += __shfl_xor(ss, o);
  __shared__ float red[4];
  if ((t & 63) == 0) red[t >> 6] = ss;
  __syncthreads();
  const float tot = red[0] + red[1] + red[2] + red[3];
  const float factor = 45.254833995939045f / (sqrtf(tot) + 1e-6f);  // sqrt(2048)
  float4 g0 = *(const float4*)(g + t * 8);
  float4 g1 = *(const float4*)(g + t * 8 + 4);
  float gg[8] = {g0.x, g0.y, g0.z, g0.w, g1.x, g1.y, g1.z, g1.w};
  short8 ov;
#pragma unroll
  for (int j = 0; j < 8; ++j) ov[j] = (short)f2bf(f[j] * factor * gg[j]);
  *(short8*)(out + base) = ov;
}

// ---------------------------------------------------------------------------
__global__ __launch_bounds__(256) void qknorm_kernel(ushort_t* __restrict__ buf, float scale) {
  const int wv = threadIdx.x >> 6;
  const int lane = threadIdx.x & 63;
  const size_t vi = (size_t)blockIdx.x * 4 + wv;
  ushort_t* p = buf + vi * 128 + lane * 2;
  const float a = bf2f(p[0]), b = bf2f(p[1]);
  float ss = a * a + b * b;
#pragma unroll
  for (int o = 32; o >= 1; o >>= 1) ss += __shfl_xor(ss, o);
  const float f = scale / (sqrtf(ss) + 1e-6f);
  p[0] = f2bf(a * f);
  p[1] = f2bf(b * f);
}

// ---------------------------------------------------------------------------
// GEMM: C[M,N] = epi(A[M,K]_bf16 · W[N,K]_bf16^T (+ RES_fp32)).
// EPI: 0 = store bf16; 1 = +RES fp32, store fp32; 2 = exact GELU, store bf16;
//      3 = store bf16 transposed per-head: vt[((b*16+h)*128+d)*S + s].
// ---------------------------------------------------------------------------
template <int EPI>
__global__ __launch_bounds__(256) void gemm_bt(const ushort_t* __restrict__ A,
                                               const ushort_t* __restrict__ W,
                                               const float* __restrict__ RES,
                                               void* __restrict__ Cv,
                                               int M, int N, int K) {
  __shared__ __align__(16) ushort_t a_lds[128 * 32];
  __shared__ __align__(16) ushort_t b_lds[128 * 32];
  const int tid = threadIdx.x;
  const int w = tid >> 6;
  const int lane = tid & 63;
  const int quad = lane >> 4;
  const int l15 = lane & 15;
  const int wr = w >> 1, wc = w & 1;
  const long bm = (long)blockIdx.y * 128;
  const long bn = (long)blockIdx.x * 128;

  const int srow = tid >> 2;
  const int scol = (tid & 3) * 8;
  const ushort_t* gA = A + (size_t)(bm + srow) * K + scol;
  const ushort_t* gB = W + (size_t)(bn + srow) * K + scol;
  ushort_t* lA = a_lds + w * 512;
  ushort_t* lB = b_lds + w * 512;
  const size_t half = (size_t)64 * K;

  f32x4 acc[4][4] = {};

  for (int k0 = 0; k0 < K; k0 += 32) {
    load_lds16(gA, lA);
    load_lds16(gA + half, lA + 2048);
    load_lds16(gB, lB);
    load_lds16(gB + half, lB + 2048);
    gA += 32; gB += 32;
    __syncthreads();
    short8 af[4], bfr[4];
#pragma unroll
    for (int i = 0; i < 4; ++i) {
      af[i]  = *(const short8*)&a_lds[(wr * 64 + i * 16 + l15) * 32 + quad * 8];
      bfr[i] = *(const short8*)&b_lds[(wc * 64 + i * 16 + l15) * 32 + quad * 8];
    }
#pragma unroll
    for (int i = 0; i < 4; ++i)
#pragma unroll
      for (int j = 0; j < 4; ++j)
        acc[i][j] = __builtin_amdgcn_mfma_f32_16x16x32_bf16(af[i], bfr[j], acc[i][j], 0, 0, 0);
    __syncthreads();
  }

#pragma unroll
  for (int i = 0; i < 4; ++i) {
    const long row0 = bm + wr * 64 + i * 16 + quad * 4;
#pragma unroll
    for (int j = 0; j < 4; ++j) {
      const long col = bn + wc * 64 + j * 16 + l15;
      if (EPI == 3) {
        // transposed per-head V: rows of acc (s) are contiguous in vt
        const long b = row0 >> 11;        // row0 / S_LEN
        const long s0 = row0 & (S_LEN - 1);
        const long h = col >> 7;
        const long d = col & (HDIM - 1);
        short4v ov;
#pragma unroll
        for (int r = 0; r < 4; ++r) ov[r] = (short)f2bf(acc[i][j][r]);
        *(short4v*)((ushort_t*)Cv + ((b * NHEAD + h) * HDIM + d) * S_LEN + s0) = ov;
      } else {
#pragma unroll
        for (int r = 0; r < 4; ++r) {
          float v = acc[i][j][r];
          const size_t idx = (size_t)(row0 + r) * N + col;
          if (EPI == 1) {
            ((float*)Cv)[idx] = v + RES[idx];
          } else if (EPI == 2) {
            v = 0.5f * v * (1.0f + erff(v * 0.70710678118654752f));
            ((ushort_t*)Cv)[idx] = f2bf(v);
          } else {
            ((ushort_t*)Cv)[idx] = f2bf(v);
          }
        }
      }
    }
  }
}

// ---------------------------------------------------------------------------
// Causal flash attention, 4 waves/block, 64-row Q tile (16 rows per wave),
// 32-key K-tiles shared across waves. K and V^T staged into LDS with
// global_load_lds (width 16). q pre-normalized+scaled; k pre-normalized;
// vt is V transposed per head: vt[b][h][d][s].
// LDS layouts (all 64B-row ds_read_b128 patterns, GEMM-proven):
//   K_lds  [db=d/32][key(32)][dlow(32)]   8 KB
//   Vt_lds [d(128)][key(32)]              8 KB
//   P_lds  per-wave [q(16)][key(32)]      4*1 KB
// ---------------------------------------------------------------------------
__global__ __launch_bounds__(256) void attn_kernel(const ushort_t* __restrict__ q,
                                                   const ushort_t* __restrict__ k,
                                                   const ushort_t* __restrict__ vt,
                                                   ushort_t* __restrict__ out) {
  __shared__ __align__(16) ushort_t K_lds[32 * 128];
  __shared__ __align__(16) ushort_t Vt_lds[128 * 32];
  __shared__ __align__(16) ushort_t P_lds[4 * 16 * 32];
  const int tid = threadIdx.x;
  const int w = tid >> 6;
  const int lane = tid & 63;
  const int quad = lane >> 4;
  const int l15 = lane & 15;

  const int qt = blockIdx.x & (S_LEN / 64 - 1);   // 32 q-tiles
  const int bh = blockIdx.x >> 5;
  const int b = bh >> 4;
  const int h = bh & 15;
  const int q0 = qt * 64;
  const int wrow0 = q0 + w * 16;                   // this wave's first q row
  const size_t base = ((size_t)b * S_LEN) * D_DIM + h * HDIM;       // q/k/out
  const size_t vtbase = ((size_t)(b * NHEAD + h)) * HDIM * S_LEN;   // vt

  // per-lane Q A-frags (16 rows x 128 d)
  short8 qa[4];
#pragma unroll
  for (int st = 0; st < 4; ++st)
    qa[st] = *(const short8*)(q + base + (size_t)(wrow0 + l15) * D_DIM + st * 32 + quad * 8);

  // staging decomposition (chunk = 16B = 8 elems); K: [db][key][32]
  const int kc0 = w * 64 + lane;            // chunk id in round 0 (0..255)
  ushort_t* Pw = P_lds + w * 512;

  f32x4 o[8] = {};
  float m[4], l[4];
#pragma unroll
  for (int r = 0; r < 4; ++r) { m[r] = -__builtin_inff(); l[r] = 0.f; }

  const int ktmax = (q0 + 63) >> 5;
  for (int kt = 0; kt <= ktmax; ++kt) {
    // ---- stage K tile (8KB) + Vt tile (8KB), 2 rounds each ----
#pragma unroll
    for (int r2 = 0; r2 < 2; ++r2) {
      const int c = r2 * 256 + kc0;
      // K chunk: db = c>>7, key = (c>>2)&31, dlow = (c&3)*8
      {
        const int db = c >> 7, key = (c >> 2) & 31, dl = (c & 3) * 8;
        load_lds16(k + base + (size_t)(kt * 32 + key) * D_DIM + db * 32 + dl,
                   K_lds + (size_t)(r2 * 4 + w) * 512);
      }
      // Vt chunk: d = c>>2, klow = (c&3)*8
      {
        const int d = c >> 2, kl = (c & 3) * 8;
        load_lds16(vt + vtbase + (size_t)d * S_LEN + kt * 32 + kl,
                   Vt_lds + (size_t)(r2 * 4 + w) * 512);
      }
    }
    __syncthreads();  // drain global_load_lds

    if (kt * 32 <= wrow0 + 15) {  // tile not fully masked for this wave
      // ---- scores S[16 q][32 key] ----
      f32x4 s[2];
#pragma unroll
      for (int h2 = 0; h2 < 2; ++h2) {
        f32x4 sa = {};
#pragma unroll
        for (int st = 0; st < 4; ++st) {
          short8 kb = *(const short8*)&K_lds[st * 1024 + (h2 * 16 + l15) * 32 + quad * 8];
          sa = __builtin_amdgcn_mfma_f32_16x16x32_bf16(qa[st], kb, sa, 0, 0, 0);
        }
        s[h2] = sa;
      }

      // ---- online softmax (per quad-row) ----
      const int key_lo = kt * 32 + l15;
      const int key_hi = key_lo + 16;
      float alpha[4];
#pragma unroll
      for (int r = 0; r < 4; ++r) {
        const int qrow = wrow0 + quad * 4 + r;
        float s0 = (key_lo <= qrow) ? s[0][r] : -__builtin_inff();
        float s1 = (key_hi <= qrow) ? s[1][r] : -__builtin_inff();
        float tmax = fmaxf(s0, s1);
#pragma unroll
        for (int off = 8; off >= 1; off >>= 1) tmax = fmaxf(tmax, __shfl_xor(tmax, off));
        const float mn = fmaxf(m[r], tmax);
        const float al = __expf(m[r] - mn);
        const float p0 = __expf(s0 - mn);
        const float p1 = __expf(s1 - mn);
        float ps = p0 + p1;
#pragma unroll
        for (int off = 8; off >= 1; off >>= 1) ps += __shfl_xor(ps, off);
        l[r] = l[r] * al + ps;
        m[r] = mn;
        alpha[r] = al;
        Pw[(quad * 4 + r) * 32 + l15] = f2bf(p0);
        Pw[(quad * 4 + r) * 32 + l15 + 16] = f2bf(p1);
      }
      // wave-private P: compiler's lgkmcnt orders write->read, no barrier

      // ---- rescale + O += P·V ----
#pragma unroll
      for (int c = 0; c < 8; ++c)
#pragma unroll
        for (int r = 0; r < 4; ++r) o[c][r] *= alpha[r];

      short8 af = *(const short8*)&Pw[l15 * 32 + quad * 8];
#pragma unroll
      for (int c = 0; c < 8; ++c) {
        short8 vb = *(const short8*)&Vt_lds[(c * 16 + l15) * 32 + quad * 8];
        o[c] = __builtin_amdgcn_mfma_f32_16x16x32_bf16(af, vb, o[c], 0, 0, 0);
      }
    }
    __syncthreads();  // protect K/Vt LDS before next staging
  }

#pragma unroll
  for (int c = 0; c < 8; ++c)
#pragma unroll
    for (int r = 0; r < 4; ++r) {
      const float val = o[c][r] / l[r];
      out[base + (size_t)(wrow0 + quad * 4 + r) * D_DIM + c * 16 + l15] = f2bf(val);
    }
}

// ---------------------------------------------------------------------------
extern "C" void kernel_launch(void* const* d_in, const int* in_sizes, int n_in,
                              void* d_out, int out_size, void* d_ws, size_t ws_size,
                              hipStream_t stream) {
  const float* hid  = (const float*)d_in[0];
  const float* Wq   = (const float*)d_in[1];
  const float* Wk   = (const float*)d_in[2];
  const float* Wv   = (const float*)d_in[3];
  const float* Wo   = (const float*)d_in[4];
  const float* Win  = (const float*)d_in[5];
  const float* Wout = (const float*)d_in[6];
  // d_in[7] = qk_norm_factor == 1/sqrt(128), folded in as exact constant.
  const float* ga   = (const float*)d_in[8];
  const float* gm   = (const float*)d_in[9];
  float* out = (float*)d_out;

  const size_t DD = (size_t)D_DIM * D_DIM;
  const size_t FD = (size_t)F_DIM * D_DIM;
  const size_t SZ = (size_t)MROWS * D_DIM;

  ushort_t* wqb  = (ushort_t*)d_ws;
  ushort_t* wkb  = wqb + DD;
  ushort_t* wvb  = wkb + DD;
  ushort_t* wob  = wvb + DD;
  ushort_t* winb = wob + DD;
  ushort_t* woutb= winb + FD;
  float*    hb   = (float*)(woutb + FD);      // h (fp32)
  ushort_t* qb   = (ushort_t*)(hb + SZ);      // q, later y_norm
  ushort_t* xb   = qb + SZ;                   // x_norm, later attn-out
  ushort_t* kb   = xb + SZ;
  ushort_t* vtb  = kb + SZ;                   // V^T per head [b][h][d][s]
  ushort_t* mid  = xb;                        // overlays xb/kb/vtb + tail

  const dim3 gD(D_DIM / 128, MROWS / 128);
  const dim3 gF(F_DIM / 128, MROWS / 128);

  f2b_kernel<<<DD / 1024, 256, 0, stream>>>(Wq, wqb);
  f2b_kernel<<<DD / 1024, 256, 0, stream>>>(Wk, wkb);
  f2b_kernel<<<DD / 1024, 256, 0, stream>>>(Wv, wvb);
  f2b_kernel<<<DD / 1024, 256, 0, stream>>>(Wo, wob);
  f2b_kernel<<<FD / 1024, 256, 0, stream>>>(Win, winb);
  f2b_kernel<<<FD / 1024, 256, 0, stream>>>(Wout, woutb);

  hsnorm_kernel<<<MROWS, 256, 0, stream>>>(hid, ga, xb);
  gemm_bt<0><<<gD, 256, 0, stream>>>(xb, wqb, nullptr, qb, MROWS, D_DIM, D_DIM);
  gemm_bt<0><<<gD, 256, 0, stream>>>(xb, wkb, nullptr, kb, MROWS, D_DIM, D_DIM);
  gemm_bt<3><<<gD, 256, 0, stream>>>(xb, wvb, nullptr, vtb, MROWS, D_DIM, D_DIM);
  qknorm_kernel<<<(MROWS * NHEAD) / 4, 256, 0, stream>>>(qb, 0.08838834764831845f);
  qknorm_kernel<<<(MROWS * NHEAD) / 4, 256, 0, stream>>>(kb, 1.0f);
  attn_kernel<<<BATCH * NHEAD * (S_LEN / 64), 256, 0, stream>>>(qb, kb, vtb, xb);
  gemm_bt<1><<<gD, 256, 0, stream>>>(xb, wob, hid, hb, MROWS, D_DIM, D_DIM);
  hsnorm_kernel<<<MROWS, 256, 0, stream>>>(hb, gm, qb);
  gemm_bt<2><<<gF, 256, 0, stream>>>(qb, winb, nullptr, mid, MROWS, F_DIM, D_DIM);
  gemm_bt<1><<<gD, 256, 0, stream>>>(mid, woutb, hb, out, MROWS, D_DIM, F_DIM);
}

// Round 4
// 1123.013 us; speedup vs baseline: 1.5172x; 1.0586x over previous
//
#include <hip/hip_runtime.h>
#include <math.h>

// ============================================================================
// HypersphereBlock (nGPT-style transformer block), MI355X / gfx950.
// I/O dtype: fp32. Internal compute: bf16 MFMA, fp32 accum.
// B=2 S=2048 D=2048 H=16 hd=128 F=8192.
// R4: attention — 64-key K-tiles (half the barriers), reversed qt dispatch
// (heavy causal blocks first), conflict-safe [kc][.][32] LDS layouts.
// ============================================================================

typedef unsigned short ushort_t;
typedef __attribute__((ext_vector_type(8))) short short8;
typedef __attribute__((ext_vector_type(4))) short short4v;
typedef __attribute__((ext_vector_type(4))) float f32x4;

#define S_LEN 2048
#define D_DIM 2048
#define F_DIM 8192
#define NHEAD 16
#define HDIM 128
#define BATCH 2
#define MROWS (BATCH * S_LEN)

__device__ __forceinline__ float bf2f(ushort_t u) {
  union { unsigned int i; float f; } c; c.i = ((unsigned int)u) << 16; return c.f;
}
__device__ __forceinline__ ushort_t f2bf(float f) {
  union { unsigned int i; float f; } c; c.f = f;
  unsigned int u = c.i;
  unsigned int r = (u + 0x7FFFu + ((u >> 16) & 1u)) >> 16;  // RNE
  return (ushort_t)r;
}
__device__ __forceinline__ void load_lds16(const ushort_t* g, ushort_t* l) {
  __builtin_amdgcn_global_load_lds((const __attribute__((address_space(1))) void*)g,
                                   (__attribute__((address_space(3))) void*)l,
                                   16, 0, 0);
}

// ---------------------------------------------------------------------------
__global__ __launch_bounds__(256) void f2b_kernel(const float* __restrict__ in,
                                                  ushort_t* __restrict__ out) {
  const size_t i = ((size_t)blockIdx.x * 256 + threadIdx.x) * 4;
  float4 v = *(const float4*)(in + i);
  short4v o;
  o[0] = (short)f2bf(v.x); o[1] = (short)f2bf(v.y);
  o[2] = (short)f2bf(v.z); o[3] = (short)f2bf(v.w);
  *(short4v*)(out + i) = o;
}

// ---------------------------------------------------------------------------
__global__ __launch_bounds__(256) void hsnorm_kernel(const float* __restrict__ x,
                                                     const float* __restrict__ g,
                                                     ushort_t* __restrict__ out) {
  const int row = blockIdx.x;
  const int t = threadIdx.x;
  const size_t base = (size_t)row * D_DIM + t * 8;
  float4 x0 = *(const float4*)(x + base);
  float4 x1 = *(const float4*)(x + base + 4);
  float f[8] = {x0.x, x0.y, x0.z, x0.w, x1.x, x1.y, x1.z, x1.w};
  float ss = 0.f;
#pragma unroll
  for (int j = 0; j < 8; ++j) ss += f[j] * f[j];
#pragma unroll
  for (int o = 32; o >= 1; o >>= 1) ss += __shfl_xor(ss, o);
  __shared__ float red[4];
  if ((t & 63) == 0) red[t >> 6] = ss;
  __syncthreads();
  const float tot = red[0] + red[1] + red[2] + red[3];
  const float factor = 45.254833995939045f / (sqrtf(tot) + 1e-6f);  // sqrt(2048)
  float4 g0 = *(const float4*)(g + t * 8);
  float4 g1 = *(const float4*)(g + t * 8 + 4);
  float gg[8] = {g0.x, g0.y, g0.z, g0.w, g1.x, g1.y, g1.z, g1.w};
  short8 ov;
#pragma unroll
  for (int j = 0; j < 8; ++j) ov[j] = (short)f2bf(f[j] * factor * gg[j]);
  *(short8*)(out + base) = ov;
}

// ---------------------------------------------------------------------------
__global__ __launch_bounds__(256) void qknorm_kernel(ushort_t* __restrict__ buf, float scale) {
  const int wv = threadIdx.x >> 6;
  const int lane = threadIdx.x & 63;
  const size_t vi = (size_t)blockIdx.x * 4 + wv;
  ushort_t* p = buf + vi * 128 + lane * 2;
  const float a = bf2f(p[0]), b = bf2f(p[1]);
  float ss = a * a + b * b;
#pragma unroll
  for (int o = 32; o >= 1; o >>= 1) ss += __shfl_xor(ss, o);
  const float f = scale / (sqrtf(ss) + 1e-6f);
  p[0] = f2bf(a * f);
  p[1] = f2bf(b * f);
}

// ---------------------------------------------------------------------------
// GEMM: C[M,N] = epi(A[M,K]_bf16 · W[N,K]_bf16^T (+ RES_fp32)).
// EPI: 0 = store bf16; 1 = +RES fp32, store fp32; 2 = exact GELU, store bf16;
//      3 = store bf16 transposed per-head: vt[((b*16+h)*128+d)*S + s].
// ---------------------------------------------------------------------------
template <int EPI>
__global__ __launch_bounds__(256) void gemm_bt(const ushort_t* __restrict__ A,
                                               const ushort_t* __restrict__ W,
                                               const float* __restrict__ RES,
                                               void* __restrict__ Cv,
                                               int M, int N, int K) {
  __shared__ __align__(16) ushort_t a_lds[128 * 32];
  __shared__ __align__(16) ushort_t b_lds[128 * 32];
  const int tid = threadIdx.x;
  const int w = tid >> 6;
  const int lane = tid & 63;
  const int quad = lane >> 4;
  const int l15 = lane & 15;
  const int wr = w >> 1, wc = w & 1;
  const long bm = (long)blockIdx.y * 128;
  const long bn = (long)blockIdx.x * 128;

  const int srow = tid >> 2;
  const int scol = (tid & 3) * 8;
  const ushort_t* gA = A + (size_t)(bm + srow) * K + scol;
  const ushort_t* gB = W + (size_t)(bn + srow) * K + scol;
  ushort_t* lA = a_lds + w * 512;
  ushort_t* lB = b_lds + w * 512;
  const size_t half = (size_t)64 * K;

  f32x4 acc[4][4] = {};

  for (int k0 = 0; k0 < K; k0 += 32) {
    load_lds16(gA, lA);
    load_lds16(gA + half, lA + 2048);
    load_lds16(gB, lB);
    load_lds16(gB + half, lB + 2048);
    gA += 32; gB += 32;
    __syncthreads();
    short8 af[4], bfr[4];
#pragma unroll
    for (int i = 0; i < 4; ++i) {
      af[i]  = *(const short8*)&a_lds[(wr * 64 + i * 16 + l15) * 32 + quad * 8];
      bfr[i] = *(const short8*)&b_lds[(wc * 64 + i * 16 + l15) * 32 + quad * 8];
    }
#pragma unroll
    for (int i = 0; i < 4; ++i)
#pragma unroll
      for (int j = 0; j < 4; ++j)
        acc[i][j] = __builtin_amdgcn_mfma_f32_16x16x32_bf16(af[i], bfr[j], acc[i][j], 0, 0, 0);
    __syncthreads();
  }

#pragma unroll
  for (int i = 0; i < 4; ++i) {
    const long row0 = bm + wr * 64 + i * 16 + quad * 4;
#pragma unroll
    for (int j = 0; j < 4; ++j) {
      const long col = bn + wc * 64 + j * 16 + l15;
      if (EPI == 3) {
        const long b = row0 >> 11;
        const long s0 = row0 & (S_LEN - 1);
        const long h = col >> 7;
        const long d = col & (HDIM - 1);
        short4v ov;
#pragma unroll
        for (int r = 0; r < 4; ++r) ov[r] = (short)f2bf(acc[i][j][r]);
        *(short4v*)((ushort_t*)Cv + ((b * NHEAD + h) * HDIM + d) * S_LEN + s0) = ov;
      } else {
#pragma unroll
        for (int r = 0; r < 4; ++r) {
          float v = acc[i][j][r];
          const size_t idx = (size_t)(row0 + r) * N + col;
          if (EPI == 1) {
            ((float*)Cv)[idx] = v + RES[idx];
          } else if (EPI == 2) {
            v = 0.5f * v * (1.0f + erff(v * 0.70710678118654752f));
            ((ushort_t*)Cv)[idx] = f2bf(v);
          } else {
            ((ushort_t*)Cv)[idx] = f2bf(v);
          }
        }
      }
    }
  }
}

// ---------------------------------------------------------------------------
// Causal flash attention. 4 waves/block, 64-row Q tile (16 rows/wave),
// 64-key K-tiles shared across waves, staged via global_load_lds (w=16).
// qt dispatch REVERSED so heavy diagonal blocks launch first.
// LDS (all reads are 64B-row ds_read_b128 patterns):
//   K_lds  [db(4)][key(64)][dlow(32)]        16 KB
//   Vt_lds [kc(2)][d(128)][keylow(32)]       16 KB
//   P_lds  per-wave [kc(2)][q(16)][klow(32)]  4*2 KB
// ---------------------------------------------------------------------------
__global__ __launch_bounds__(256) void attn_kernel(const ushort_t* __restrict__ q,
                                                   const ushort_t* __restrict__ k,
                                                   const ushort_t* __restrict__ vt,
                                                   ushort_t* __restrict__ out) {
  __shared__ __align__(16) ushort_t K_lds[64 * 128];
  __shared__ __align__(16) ushort_t Vt_lds[128 * 64];
  __shared__ __align__(16) ushort_t P_lds[4 * 16 * 64];
  const int tid = threadIdx.x;
  const int w = tid >> 6;
  const int lane = tid & 63;
  const int quad = lane >> 4;
  const int l15 = lane & 15;

  const int qt = (S_LEN / 64 - 1) - (blockIdx.x & (S_LEN / 64 - 1));  // reversed
  const int bh = blockIdx.x >> 5;
  const int b = bh >> 4;
  const int h = bh & 15;
  const int q0 = qt * 64;
  const int wrow0 = q0 + w * 16;
  const size_t base = ((size_t)b * S_LEN) * D_DIM + h * HDIM;       // q/k/out
  const size_t vtbase = ((size_t)(b * NHEAD + h)) * HDIM * S_LEN;   // vt

  short8 qa[4];
#pragma unroll
  for (int st = 0; st < 4; ++st)
    qa[st] = *(const short8*)(q + base + (size_t)(wrow0 + l15) * D_DIM + st * 32 + quad * 8);

  const int kc0 = w * 64 + lane;   // chunk id in round 0 (0..255), 16B chunks
  ushort_t* Pw = P_lds + w * 1024;

  f32x4 o[8] = {};
  float m[4], l[4];
#pragma unroll
  for (int r = 0; r < 4; ++r) { m[r] = -__builtin_inff(); l[r] = 0.f; }

  const int ktmax = (q0 + 63) >> 6;
  for (int kt = 0; kt <= ktmax; ++kt) {
    // ---- stage K tile (16KB, 1024 chunks) + Vt tile (16KB), 4 rounds each ----
#pragma unroll
    for (int r2 = 0; r2 < 4; ++r2) {
      const int c = r2 * 256 + kc0;
      {  // K chunk: [db][key][dlow], identity-linear: elems = 8c
        const int db = c >> 8, key = (c >> 2) & 63, dl = (c & 3) * 8;
        load_lds16(k + base + (size_t)(kt * 64 + key) * D_DIM + db * 32 + dl,
                   K_lds + (size_t)(r2 * 4 + w) * 512);
      }
      {  // Vt chunk: [kc][d][klow], identity-linear: elems = 8c
        const int kc = c >> 9, d = (c >> 2) & 127, kl = (c & 3) * 8;
        load_lds16(vt + vtbase + (size_t)d * S_LEN + kt * 64 + kc * 32 + kl,
                   Vt_lds + (size_t)(r2 * 4 + w) * 512);
      }
    }
    __syncthreads();  // drain global_load_lds

    if (kt * 64 <= wrow0 + 15) {
      // ---- scores S[16 q][64 key] ----
      f32x4 s[4];
#pragma unroll
      for (int h2 = 0; h2 < 4; ++h2) {
        f32x4 sa = {};
#pragma unroll
        for (int st = 0; st < 4; ++st) {
          short8 kb = *(const short8*)&K_lds[st * 2048 + (h2 * 16 + l15) * 32 + quad * 8];
          sa = __builtin_amdgcn_mfma_f32_16x16x32_bf16(qa[st], kb, sa, 0, 0, 0);
        }
        s[h2] = sa;
      }

      // ---- online softmax (per quad-row); key(h2) = kt*64 + h2*16 + l15 ----
      const int kbase = kt * 64 + l15;
      float alpha[4];
#pragma unroll
      for (int r = 0; r < 4; ++r) {
        const int qrow = wrow0 + quad * 4 + r;
        float sv[4];
#pragma unroll
        for (int h2 = 0; h2 < 4; ++h2)
          sv[h2] = (kbase + h2 * 16 <= qrow) ? s[h2][r] : -__builtin_inff();
        float tmax = fmaxf(fmaxf(sv[0], sv[1]), fmaxf(sv[2], sv[3]));
#pragma unroll
        for (int off = 8; off >= 1; off >>= 1) tmax = fmaxf(tmax, __shfl_xor(tmax, off));
        const float mn = fmaxf(m[r], tmax);
        const float al = __expf(m[r] - mn);
        float p[4], ps = 0.f;
#pragma unroll
        for (int h2 = 0; h2 < 4; ++h2) { p[h2] = __expf(sv[h2] - mn); ps += p[h2]; }
#pragma unroll
        for (int off = 8; off >= 1; off >>= 1) ps += __shfl_xor(ps, off);
        l[r] = l[r] * al + ps;
        m[r] = mn;
        alpha[r] = al;
#pragma unroll
        for (int h2 = 0; h2 < 4; ++h2)
          Pw[(h2 >> 1) * 512 + (quad * 4 + r) * 32 + (h2 & 1) * 16 + l15] = f2bf(p[h2]);
      }
      // wave-private P: compiler lgkmcnt orders write->read, no barrier

      // ---- rescale + O += P·V (K=64: two 32-key chunks) ----
#pragma unroll
      for (int c = 0; c < 8; ++c)
#pragma unroll
        for (int r = 0; r < 4; ++r) o[c][r] *= alpha[r];

      short8 af0 = *(const short8*)&Pw[l15 * 32 + quad * 8];
      short8 af1 = *(const short8*)&Pw[512 + l15 * 32 + quad * 8];
#pragma unroll
      for (int c = 0; c < 8; ++c) {
        short8 vb0 = *(const short8*)&Vt_lds[(c * 16 + l15) * 32 + quad * 8];
        o[c] = __builtin_amdgcn_mfma_f32_16x16x32_bf16(af0, vb0, o[c], 0, 0, 0);
        short8 vb1 = *(const short8*)&Vt_lds[4096 + (c * 16 + l15) * 32 + quad * 8];
        o[c] = __builtin_amdgcn_mfma_f32_16x16x32_bf16(af1, vb1, o[c], 0, 0, 0);
      }
    }
    __syncthreads();  // protect K/Vt LDS before next staging
  }

#pragma unroll
  for (int c = 0; c < 8; ++c)
#pragma unroll
    for (int r = 0; r < 4; ++r) {
      const float val = o[c][r] / l[r];
      out[base + (size_t)(wrow0 + quad * 4 + r) * D_DIM + c * 16 + l15] = f2bf(val);
    }
}

// ---------------------------------------------------------------------------
extern "C" void kernel_launch(void* const* d_in, const int* in_sizes, int n_in,
                              void* d_out, int out_size, void* d_ws, size_t ws_size,
                              hipStream_t stream) {
  const float* hid  = (const float*)d_in[0];
  const float* Wq   = (const float*)d_in[1];
  const float* Wk   = (const float*)d_in[2];
  const float* Wv   = (const float*)d_in[3];
  const float* Wo   = (const float*)d_in[4];
  const float* Win  = (const float*)d_in[5];
  const float* Wout = (const float*)d_in[6];
  // d_in[7] = qk_norm_factor == 1/sqrt(128), folded in as exact constant.
  const float* ga   = (const float*)d_in[8];
  const float* gm   = (const float*)d_in[9];
  float* out = (float*)d_out;

  const size_t DD = (size_t)D_DIM * D_DIM;
  const size_t FD = (size_t)F_DIM * D_DIM;
  const size_t SZ = (size_t)MROWS * D_DIM;

  ushort_t* wqb  = (ushort_t*)d_ws;
  ushort_t* wkb  = wqb + DD;
  ushort_t* wvb  = wkb + DD;
  ushort_t* wob  = wvb + DD;
  ushort_t* winb = wob + DD;
  ushort_t* woutb= winb + FD;
  float*    hb   = (float*)(woutb + FD);      // h (fp32)
  ushort_t* qb   = (ushort_t*)(hb + SZ);      // q, later y_norm
  ushort_t* xb   = qb + SZ;                   // x_norm, later attn-out
  ushort_t* kb   = xb + SZ;
  ushort_t* vtb  = kb + SZ;                   // V^T per head [b][h][d][s]
  ushort_t* mid  = xb;                        // overlays xb/kb/vtb + tail

  const dim3 gD(D_DIM / 128, MROWS / 128);
  const dim3 gF(F_DIM / 128, MROWS / 128);

  f2b_kernel<<<DD / 1024, 256, 0, stream>>>(Wq, wqb);
  f2b_kernel<<<DD / 1024, 256, 0, stream>>>(Wk, wkb);
  f2b_kernel<<<DD / 1024, 256, 0, stream>>>(Wv, wvb);
  f2b_kernel<<<DD / 1024, 256, 0, stream>>>(Wo, wob);
  f2b_kernel<<<FD / 1024, 256, 0, stream>>>(Win, winb);
  f2b_kernel<<<FD / 1024, 256, 0, stream>>>(Wout, woutb);

  hsnorm_kernel<<<MROWS, 256, 0, stream>>>(hid, ga, xb);
  gemm_bt<0><<<gD, 256, 0, stream>>>(xb, wqb, nullptr, qb, MROWS, D_DIM, D_DIM);
  gemm_bt<0><<<gD, 256, 0, stream>>>(xb, wkb, nullptr, kb, MROWS, D_DIM, D_DIM);
  gemm_bt<3><<<gD, 256, 0, stream>>>(xb, wvb, nullptr, vtb, MROWS, D_DIM, D_DIM);
  qknorm_kernel<<<(MROWS * NHEAD) / 4, 256, 0, stream>>>(qb, 0.08838834764831845f);
  qknorm_kernel<<<(MROWS * NHEAD) / 4, 256, 0, stream>>>(kb, 1.0f);
  attn_kernel<<<BATCH * NHEAD * (S_LEN / 64), 256, 0, stream>>>(qb, kb, vtb, xb);
  gemm_bt<1><<<gD, 256, 0, stream>>>(xb, wob, hid, hb, MROWS, D_DIM, D_DIM);
  hsnorm_kernel<<<MROWS, 256, 0, stream>>>(hb, gm, qb);
  gemm_bt<2><<<gF, 256, 0, stream>>>(qb, winb, nullptr, mid, MROWS, F_DIM, D_DIM);
  gemm_bt<1><<<gD, 256, 0, stream>>>(mid, woutb, hb, out, MROWS, D_DIM, F_DIM);
}

// Round 5
// 1082.286 us; speedup vs baseline: 1.5743x; 1.0376x over previous
//
#include <hip/hip_runtime.h>
#include <math.h>

// ============================================================================
// HypersphereBlock (nGPT-style transformer block), MI355X / gfx950.
// I/O dtype: fp32. Internal compute: bf16 MFMA, fp32 accum.
// B=2 S=2048 D=2048 H=16 hd=128 F=8192.
// R5: GEMM grids swapped to m-fast (L2 working-set fit), QKV fused into one
// N=6144 GEMM with routing epilogue (q / k / v^T-per-head).
// ws: bf16 W 100.7M | hb f32 33.5M | qb 16.8 | kb 16.8 | vtb 16.8 | xb 16.8
//     | 16.7 tail; mid(67MB) overlays kb..tail. => 218.1 MB.
// ============================================================================

typedef unsigned short ushort_t;
typedef __attribute__((ext_vector_type(8))) short short8;
typedef __attribute__((ext_vector_type(4))) short short4v;
typedef __attribute__((ext_vector_type(4))) float f32x4;

#define S_LEN 2048
#define D_DIM 2048
#define F_DIM 8192
#define NHEAD 16
#define HDIM 128
#define BATCH 2
#define MROWS (BATCH * S_LEN)

__device__ __forceinline__ float bf2f(ushort_t u) {
  union { unsigned int i; float f; } c; c.i = ((unsigned int)u) << 16; return c.f;
}
__device__ __forceinline__ ushort_t f2bf(float f) {
  union { unsigned int i; float f; } c; c.f = f;
  unsigned int u = c.i;
  unsigned int r = (u + 0x7FFFu + ((u >> 16) & 1u)) >> 16;  // RNE
  return (ushort_t)r;
}
__device__ __forceinline__ void load_lds16(const ushort_t* g, ushort_t* l) {
  __builtin_amdgcn_global_load_lds((const __attribute__((address_space(1))) void*)g,
                                   (__attribute__((address_space(3))) void*)l,
                                   16, 0, 0);
}

// ---------------------------------------------------------------------------
__global__ __launch_bounds__(256) void f2b_kernel(const float* __restrict__ in,
                                                  ushort_t* __restrict__ out) {
  const size_t i = ((size_t)blockIdx.x * 256 + threadIdx.x) * 4;
  float4 v = *(const float4*)(in + i);
  short4v o;
  o[0] = (short)f2bf(v.x); o[1] = (short)f2bf(v.y);
  o[2] = (short)f2bf(v.z); o[3] = (short)f2bf(v.w);
  *(short4v*)(out + i) = o;
}

// ---------------------------------------------------------------------------
__global__ __launch_bounds__(256) void hsnorm_kernel(const float* __restrict__ x,
                                                     const float* __restrict__ g,
                                                     ushort_t* __restrict__ out) {
  const int row = blockIdx.x;
  const int t = threadIdx.x;
  const size_t base = (size_t)row * D_DIM + t * 8;
  float4 x0 = *(const float4*)(x + base);
  float4 x1 = *(const float4*)(x + base + 4);
  float f[8] = {x0.x, x0.y, x0.z, x0.w, x1.x, x1.y, x1.z, x1.w};
  float ss = 0.f;
#pragma unroll
  for (int j = 0; j < 8; ++j) ss += f[j] * f[j];
#pragma unroll
  for (int o = 32; o >= 1; o >>= 1) ss += __shfl_xor(ss, o);
  __shared__ float red[4];
  if ((t & 63) == 0) red[t >> 6] = ss;
  __syncthreads();
  const float tot = red[0] + red[1] + red[2] + red[3];
  const float factor = 45.254833995939045f / (sqrtf(tot) + 1e-6f);  // sqrt(2048)
  float4 g0 = *(const float4*)(g + t * 8);
  float4 g1 = *(const float4*)(g + t * 8 + 4);
  float gg[8] = {g0.x, g0.y, g0.z, g0.w, g1.x, g1.y, g1.z, g1.w};
  short8 ov;
#pragma unroll
  for (int j = 0; j < 8; ++j) ov[j] = (short)f2bf(f[j] * factor * gg[j]);
  *(short8*)(out + base) = ov;
}

// ---------------------------------------------------------------------------
__global__ __launch_bounds__(256) void qknorm_kernel(ushort_t* __restrict__ buf, float scale) {
  const int wv = threadIdx.x >> 6;
  const int lane = threadIdx.x & 63;
  const size_t vi = (size_t)blockIdx.x * 4 + wv;
  ushort_t* p = buf + vi * 128 + lane * 2;
  const float a = bf2f(p[0]), b = bf2f(p[1]);
  float ss = a * a + b * b;
#pragma unroll
  for (int o = 32; o >= 1; o >>= 1) ss += __shfl_xor(ss, o);
  const float f = scale / (sqrtf(ss) + 1e-6f);
  p[0] = f2bf(a * f);
  p[1] = f2bf(b * f);
}

// ---------------------------------------------------------------------------
// GEMM: C[M,N] = epi(A[M,K]_bf16 · W[N,K]_bf16^T (+ RES_fp32)).
// Grid: (M/128, N/128) — m is the FAST dim (L2 working-set fit).
// EPI: 1 = +RES fp32, store fp32; 2 = exact GELU, store bf16;
//      4 = fused-QKV routing: col<2048 -> q (bf16, stride 2048);
//          col<4096 -> k (bf16); else v^T per head (Cv + 2*SZ).
// ---------------------------------------------------------------------------
template <int EPI>
__global__ __launch_bounds__(256) void gemm_bt(const ushort_t* __restrict__ A,
                                               const ushort_t* __restrict__ W,
                                               const float* __restrict__ RES,
                                               void* __restrict__ Cv,
                                               int M, int N, int K) {
  __shared__ __align__(16) ushort_t a_lds[128 * 32];
  __shared__ __align__(16) ushort_t b_lds[128 * 32];
  const int tid = threadIdx.x;
  const int w = tid >> 6;
  const int lane = tid & 63;
  const int quad = lane >> 4;
  const int l15 = lane & 15;
  const int wr = w >> 1, wc = w & 1;
  const long bm = (long)blockIdx.x * 128;   // m fast
  const long bn = (long)blockIdx.y * 128;

  const int srow = tid >> 2;
  const int scol = (tid & 3) * 8;
  const ushort_t* gA = A + (size_t)(bm + srow) * K + scol;
  const ushort_t* gB = W + (size_t)(bn + srow) * K + scol;
  ushort_t* lA = a_lds + w * 512;
  ushort_t* lB = b_lds + w * 512;
  const size_t half = (size_t)64 * K;

  f32x4 acc[4][4] = {};

  for (int k0 = 0; k0 < K; k0 += 32) {
    load_lds16(gA, lA);
    load_lds16(gA + half, lA + 2048);
    load_lds16(gB, lB);
    load_lds16(gB + half, lB + 2048);
    gA += 32; gB += 32;
    __syncthreads();
    short8 af[4], bfr[4];
#pragma unroll
    for (int i = 0; i < 4; ++i) {
      af[i]  = *(const short8*)&a_lds[(wr * 64 + i * 16 + l15) * 32 + quad * 8];
      bfr[i] = *(const short8*)&b_lds[(wc * 64 + i * 16 + l15) * 32 + quad * 8];
    }
#pragma unroll
    for (int i = 0; i < 4; ++i)
#pragma unroll
      for (int j = 0; j < 4; ++j)
        acc[i][j] = __builtin_amdgcn_mfma_f32_16x16x32_bf16(af[i], bfr[j], acc[i][j], 0, 0, 0);
    __syncthreads();
  }

  const size_t SZq = (size_t)MROWS * D_DIM;
#pragma unroll
  for (int i = 0; i < 4; ++i) {
    const long row0 = bm + wr * 64 + i * 16 + quad * 4;
#pragma unroll
    for (int j = 0; j < 4; ++j) {
      const long col = bn + wc * 64 + j * 16 + l15;
      if (EPI == 4) {
        if (col < 4096) {  // q or k, row-major stride D_DIM
          ushort_t* dst = (ushort_t*)Cv + (col < 2048 ? 0 : SZq);
          const long c = col & (D_DIM - 1);
#pragma unroll
          for (int r = 0; r < 4; ++r)
            dst[(size_t)(row0 + r) * D_DIM + c] = f2bf(acc[i][j][r]);
        } else {           // v^T per head: vt[((b*16+h)*128+d)*S + s]
          const long b = row0 >> 11;
          const long s0 = row0 & (S_LEN - 1);
          const long h = (col >> 7) & 15;
          const long d = col & (HDIM - 1);
          short4v ov;
#pragma unroll
          for (int r = 0; r < 4; ++r) ov[r] = (short)f2bf(acc[i][j][r]);
          *(short4v*)((ushort_t*)Cv + 2 * SZq + ((b * NHEAD + h) * HDIM + d) * S_LEN + s0) = ov;
        }
      } else {
#pragma unroll
        for (int r = 0; r < 4; ++r) {
          float v = acc[i][j][r];
          const size_t idx = (size_t)(row0 + r) * N + col;
          if (EPI == 1) {
            ((float*)Cv)[idx] = v + RES[idx];
          } else if (EPI == 2) {
            v = 0.5f * v * (1.0f + erff(v * 0.70710678118654752f));
            ((ushort_t*)Cv)[idx] = f2bf(v);
          }
        }
      }
    }
  }
}

// ---------------------------------------------------------------------------
// Causal flash attention. 4 waves/block, 64-row Q tile (16 rows/wave),
// 64-key K-tiles shared across waves, staged via global_load_lds (w=16).
// qt dispatch REVERSED so heavy diagonal blocks launch first.
// ---------------------------------------------------------------------------
__global__ __launch_bounds__(256) void attn_kernel(const ushort_t* __restrict__ q,
                                                   const ushort_t* __restrict__ k,
                                                   const ushort_t* __restrict__ vt,
                                                   ushort_t* __restrict__ out) {
  __shared__ __align__(16) ushort_t K_lds[64 * 128];
  __shared__ __align__(16) ushort_t Vt_lds[128 * 64];
  __shared__ __align__(16) ushort_t P_lds[4 * 16 * 64];
  const int tid = threadIdx.x;
  const int w = tid >> 6;
  const int lane = tid & 63;
  const int quad = lane >> 4;
  const int l15 = lane & 15;

  const int qt = (S_LEN / 64 - 1) - (blockIdx.x & (S_LEN / 64 - 1));  // reversed
  const int bh = blockIdx.x >> 5;
  const int b = bh >> 4;
  const int h = bh & 15;
  const int q0 = qt * 64;
  const int wrow0 = q0 + w * 16;
  const size_t base = ((size_t)b * S_LEN) * D_DIM + h * HDIM;
  const size_t vtbase = ((size_t)(b * NHEAD + h)) * HDIM * S_LEN;

  short8 qa[4];
#pragma unroll
  for (int st = 0; st < 4; ++st)
    qa[st] = *(const short8*)(q + base + (size_t)(wrow0 + l15) * D_DIM + st * 32 + quad * 8);

  const int kc0 = w * 64 + lane;
  ushort_t* Pw = P_lds + w * 1024;

  f32x4 o[8] = {};
  float m[4], l[4];
#pragma unroll
  for (int r = 0; r < 4; ++r) { m[r] = -__builtin_inff(); l[r] = 0.f; }

  const int ktmax = (q0 + 63) >> 6;
  for (int kt = 0; kt <= ktmax; ++kt) {
#pragma unroll
    for (int r2 = 0; r2 < 4; ++r2) {
      const int c = r2 * 256 + kc0;
      {
        const int db = c >> 8, key = (c >> 2) & 63, dl = (c & 3) * 8;
        load_lds16(k + base + (size_t)(kt * 64 + key) * D_DIM + db * 32 + dl,
                   K_lds + (size_t)(r2 * 4 + w) * 512);
      }
      {
        const int kc = c >> 9, d = (c >> 2) & 127, kl = (c & 3) * 8;
        load_lds16(vt + vtbase + (size_t)d * S_LEN + kt * 64 + kc * 32 + kl,
                   Vt_lds + (size_t)(r2 * 4 + w) * 512);
      }
    }
    __syncthreads();

    if (kt * 64 <= wrow0 + 15) {
      f32x4 s[4];
#pragma unroll
      for (int h2 = 0; h2 < 4; ++h2) {
        f32x4 sa = {};
#pragma unroll
        for (int st = 0; st < 4; ++st) {
          short8 kb = *(const short8*)&K_lds[st * 2048 + (h2 * 16 + l15) * 32 + quad * 8];
          sa = __builtin_amdgcn_mfma_f32_16x16x32_bf16(qa[st], kb, sa, 0, 0, 0);
        }
        s[h2] = sa;
      }

      const int kbase = kt * 64 + l15;
      float alpha[4];
#pragma unroll
      for (int r = 0; r < 4; ++r) {
        const int qrow = wrow0 + quad * 4 + r;
        float sv[4];
#pragma unroll
        for (int h2 = 0; h2 < 4; ++h2)
          sv[h2] = (kbase + h2 * 16 <= qrow) ? s[h2][r] : -__builtin_inff();
        float tmax = fmaxf(fmaxf(sv[0], sv[1]), fmaxf(sv[2], sv[3]));
#pragma unroll
        for (int off = 8; off >= 1; off >>= 1) tmax = fmaxf(tmax, __shfl_xor(tmax, off));
        const float mn = fmaxf(m[r], tmax);
        const float al = __expf(m[r] - mn);
        float p[4], ps = 0.f;
#pragma unroll
        for (int h2 = 0; h2 < 4; ++h2) { p[h2] = __expf(sv[h2] - mn); ps += p[h2]; }
#pragma unroll
        for (int off = 8; off >= 1; off >>= 1) ps += __shfl_xor(ps, off);
        l[r] = l[r] * al + ps;
        m[r] = mn;
        alpha[r] = al;
#pragma unroll
        for (int h2 = 0; h2 < 4; ++h2)
          Pw[(h2 >> 1) * 512 + (quad * 4 + r) * 32 + (h2 & 1) * 16 + l15] = f2bf(p[h2]);
      }

#pragma unroll
      for (int c = 0; c < 8; ++c)
#pragma unroll
        for (int r = 0; r < 4; ++r) o[c][r] *= alpha[r];

      short8 af0 = *(const short8*)&Pw[l15 * 32 + quad * 8];
      short8 af1 = *(const short8*)&Pw[512 + l15 * 32 + quad * 8];
#pragma unroll
      for (int c = 0; c < 8; ++c) {
        short8 vb0 = *(const short8*)&Vt_lds[(c * 16 + l15) * 32 + quad * 8];
        o[c] = __builtin_amdgcn_mfma_f32_16x16x32_bf16(af0, vb0, o[c], 0, 0, 0);
        short8 vb1 = *(const short8*)&Vt_lds[4096 + (c * 16 + l15) * 32 + quad * 8];
        o[c] = __builtin_amdgcn_mfma_f32_16x16x32_bf16(af1, vb1, o[c], 0, 0, 0);
      }
    }
    __syncthreads();
  }

#pragma unroll
  for (int c = 0; c < 8; ++c)
#pragma unroll
    for (int r = 0; r < 4; ++r) {
      const float val = o[c][r] / l[r];
      out[base + (size_t)(wrow0 + quad * 4 + r) * D_DIM + c * 16 + l15] = f2bf(val);
    }
}

// ---------------------------------------------------------------------------
extern "C" void kernel_launch(void* const* d_in, const int* in_sizes, int n_in,
                              void* d_out, int out_size, void* d_ws, size_t ws_size,
                              hipStream_t stream) {
  const float* hid  = (const float*)d_in[0];
  const float* Wq   = (const float*)d_in[1];
  const float* Wk   = (const float*)d_in[2];
  const float* Wv   = (const float*)d_in[3];
  const float* Wo   = (const float*)d_in[4];
  const float* Win  = (const float*)d_in[5];
  const float* Wout = (const float*)d_in[6];
  // d_in[7] = qk_norm_factor == 1/sqrt(128), folded in as exact constant.
  const float* ga   = (const float*)d_in[8];
  const float* gm   = (const float*)d_in[9];
  float* out = (float*)d_out;

  const size_t DD = (size_t)D_DIM * D_DIM;
  const size_t FD = (size_t)F_DIM * D_DIM;
  const size_t SZ = (size_t)MROWS * D_DIM;

  ushort_t* wqb  = (ushort_t*)d_ws;     // wq|wk|wv contiguous = stacked [6144,2048]
  ushort_t* wkb  = wqb + DD;
  ushort_t* wvb  = wkb + DD;
  ushort_t* wob  = wvb + DD;
  ushort_t* winb = wob + DD;
  ushort_t* woutb= winb + FD;
  float*    hb   = (float*)(woutb + FD);      // h (fp32)
  ushort_t* qb   = (ushort_t*)(hb + SZ);      // q, later y_norm
  ushort_t* kb   = qb + SZ;                   // k      (qb+SZ: EPI4 contract)
  ushort_t* vtb  = kb + SZ;                   // v^T per head (qb+2SZ)
  ushort_t* xb   = vtb + SZ;                  // x_norm, later attn-out
  ushort_t* mid  = kb;                        // 67MB, overlays kb|vtb|xb + tail

  f2b_kernel<<<DD / 1024, 256, 0, stream>>>(Wq, wqb);
  f2b_kernel<<<DD / 1024, 256, 0, stream>>>(Wk, wkb);
  f2b_kernel<<<DD / 1024, 256, 0, stream>>>(Wv, wvb);
  f2b_kernel<<<DD / 1024, 256, 0, stream>>>(Wo, wob);
  f2b_kernel<<<FD / 1024, 256, 0, stream>>>(Win, winb);
  f2b_kernel<<<FD / 1024, 256, 0, stream>>>(Wout, woutb);

  hsnorm_kernel<<<MROWS, 256, 0, stream>>>(hid, ga, xb);
  // fused QKV: A=xb, W=[Wq;Wk;Wv] stacked, routed epilogue
  gemm_bt<4><<<dim3(MROWS / 128, 6144 / 128), 256, 0, stream>>>(
      xb, wqb, nullptr, qb, MROWS, 6144, D_DIM);
  qknorm_kernel<<<(MROWS * NHEAD) / 4, 256, 0, stream>>>(qb, 0.08838834764831845f);
  qknorm_kernel<<<(MROWS * NHEAD) / 4, 256, 0, stream>>>(kb, 1.0f);
  attn_kernel<<<BATCH * NHEAD * (S_LEN / 64), 256, 0, stream>>>(qb, kb, vtb, xb);
  gemm_bt<1><<<dim3(MROWS / 128, D_DIM / 128), 256, 0, stream>>>(
      xb, wob, hid, hb, MROWS, D_DIM, D_DIM);
  hsnorm_kernel<<<MROWS, 256, 0, stream>>>(hb, gm, qb);
  gemm_bt<2><<<dim3(MROWS / 128, F_DIM / 128), 256, 0, stream>>>(
      qb, winb, nullptr, mid, MROWS, F_DIM, D_DIM);
  gemm_bt<1><<<dim3(MROWS / 128, D_DIM / 128), 256, 0, stream>>>(
      mid, woutb, hb, out, MROWS, D_DIM, F_DIM);
}

// Round 7
// 998.762 us; speedup vs baseline: 1.7060x; 1.0836x over previous
//
#include <hip/hip_runtime.h>
#include <math.h>

// ============================================================================
// HypersphereBlock (nGPT-style transformer block), MI355X / gfx950.
// I/O dtype: fp32. Internal compute: bf16 MFMA, fp32 accum.
// B=2 S=2048 D=2048 H=16 hd=128 F=8192.
// R7: BK=64 K-loop with EXPLICIT +32-elem pointers for the second K-half
// (R6's builtin offset-arg produced NaN — do NOT use global_load_lds's
// 4th arg for global offsets; let the compiler fold pointer arithmetic).
// Merged single f2b kernel. Attention unchanged from R5.
// ws: bf16 W 100.7M | hb f32 33.5M | qb 16.8 | kb 16.8 | vtb 16.8 | xb 16.8
//     | 16.7 tail; mid(67MB) overlays kb..tail. => 218.1 MB.
// ============================================================================

typedef unsigned short ushort_t;
typedef __attribute__((ext_vector_type(8))) short short8;
typedef __attribute__((ext_vector_type(4))) short short4v;
typedef __attribute__((ext_vector_type(4))) float f32x4;

#define S_LEN 2048
#define D_DIM 2048
#define F_DIM 8192
#define NHEAD 16
#define HDIM 128
#define BATCH 2
#define MROWS (BATCH * S_LEN)

__device__ __forceinline__ float bf2f(ushort_t u) {
  union { unsigned int i; float f; } c; c.i = ((unsigned int)u) << 16; return c.f;
}
__device__ __forceinline__ ushort_t f2bf(float f) {
  union { unsigned int i; float f; } c; c.f = f;
  unsigned int u = c.i;
  unsigned int r = (u + 0x7FFFu + ((u >> 16) & 1u)) >> 16;  // RNE
  return (ushort_t)r;
}
__device__ __forceinline__ void load_lds16(const ushort_t* g, ushort_t* l) {
  __builtin_amdgcn_global_load_lds((const __attribute__((address_space(1))) void*)g,
                                   (__attribute__((address_space(3))) void*)l,
                                   16, 0, 0);
}

// ---------------------------------------------------------------------------
// merged fp32->bf16 weight conversion. Outputs contiguous in ws:
// [Wq|Wk|Wv|Wo (4xDD)][Win|Wout (2xFD)]. 4 elems/thread.
// ---------------------------------------------------------------------------
__global__ __launch_bounds__(256) void f2b_all_kernel(const float* __restrict__ wq,
                                                      const float* __restrict__ wk,
                                                      const float* __restrict__ wv,
                                                      const float* __restrict__ wo,
                                                      const float* __restrict__ wi,
                                                      const float* __restrict__ wu,
                                                      ushort_t* __restrict__ out) {
  const size_t DD = (size_t)D_DIM * D_DIM;
  const size_t FD = (size_t)F_DIM * D_DIM;
  const size_t e = ((size_t)blockIdx.x * 256 + threadIdx.x) * 4;  // concat elem idx
  const float* src;
  size_t off;
  if (e < 4 * DD) {
    const int wsel = (int)(e >> 22);                  // e / DD
    src = (wsel == 0) ? wq : (wsel == 1) ? wk : (wsel == 2) ? wv : wo;
    off = e & (DD - 1);
  } else if (e < 4 * DD + FD) {
    src = wi; off = e - 4 * DD;
  } else {
    src = wu; off = e - 4 * DD - FD;
  }
  float4 v = *(const float4*)(src + off);
  short4v o;
  o[0] = (short)f2bf(v.x); o[1] = (short)f2bf(v.y);
  o[2] = (short)f2bf(v.z); o[3] = (short)f2bf(v.w);
  *(short4v*)(out + e) = o;
}

// ---------------------------------------------------------------------------
__global__ __launch_bounds__(256) void hsnorm_kernel(const float* __restrict__ x,
                                                     const float* __restrict__ g,
                                                     ushort_t* __restrict__ out) {
  const int row = blockIdx.x;
  const int t = threadIdx.x;
  const size_t base = (size_t)row * D_DIM + t * 8;
  float4 x0 = *(const float4*)(x + base);
  float4 x1 = *(const float4*)(x + base + 4);
  float f[8] = {x0.x, x0.y, x0.z, x0.w, x1.x, x1.y, x1.z, x1.w};
  float ss = 0.f;
#pragma unroll
  for (int j = 0; j < 8; ++j) ss += f[j] * f[j];
#pragma unroll
  for (int o = 32; o >= 1; o >>= 1) ss += __shfl_xor(ss, o);
  __shared__ float red[4];
  if ((t & 63) == 0) red[t >> 6] = ss;
  __syncthreads();
  const float tot = red[0] + red[1] + red[2] + red[3];
  const float factor = 45.254833995939045f / (sqrtf(tot) + 1e-6f);  // sqrt(2048)
  float4 g0 = *(const float4*)(g + t * 8);
  float4 g1 = *(const float4*)(g + t * 8 + 4);
  float gg[8] = {g0.x, g0.y, g0.z, g0.w, g1.x, g1.y, g1.z, g1.w};
  short8 ov;
#pragma unroll
  for (int j = 0; j < 8; ++j) ov[j] = (short)f2bf(f[j] * factor * gg[j]);
  *(short8*)(out + base) = ov;
}

// ---------------------------------------------------------------------------
__global__ __launch_bounds__(256) void qknorm_kernel(ushort_t* __restrict__ buf, float scale) {
  const int wv = threadIdx.x >> 6;
  const int lane = threadIdx.x & 63;
  const size_t vi = (size_t)blockIdx.x * 4 + wv;
  ushort_t* p = buf + vi * 128 + lane * 2;
  const float a = bf2f(p[0]), b = bf2f(p[1]);
  float ss = a * a + b * b;
#pragma unroll
  for (int o = 32; o >= 1; o >>= 1) ss += __shfl_xor(ss, o);
  const float f = scale / (sqrtf(ss) + 1e-6f);
  p[0] = f2bf(a * f);
  p[1] = f2bf(b * f);
}

// ---------------------------------------------------------------------------
// GEMM: C[M,N] = epi(A[M,K]_bf16 · W[N,K]_bf16^T (+ RES_fp32)).
// Grid: (M/128, N/128) — m fast. BK=64: LDS [kk][row][32] sub-tiles so all
// ds_read_b128 keep the 64B-row phase pattern. Second K-half loaded via
// explicit gA+32 / gB+32 pointers (compiler folds into inst offset).
// EPI: 1 = +RES fp32, store fp32; 2 = exact GELU, store bf16;
//      4 = fused-QKV routing: q | k | v^T-per-head.
// ---------------------------------------------------------------------------
template <int EPI>
__global__ __launch_bounds__(256) void gemm_bt(const ushort_t* __restrict__ A,
                                               const ushort_t* __restrict__ W,
                                               const float* __restrict__ RES,
                                               void* __restrict__ Cv,
                                               int M, int N, int K) {
  __shared__ __align__(16) ushort_t a_lds[128 * 64];   // [kk][row][32]
  __shared__ __align__(16) ushort_t b_lds[128 * 64];
  const int tid = threadIdx.x;
  const int w = tid >> 6;
  const int lane = tid & 63;
  const int quad = lane >> 4;
  const int l15 = lane & 15;
  const int wr = w >> 1, wc = w & 1;
  const long bm = (long)blockIdx.x * 128;   // m fast
  const long bn = (long)blockIdx.y * 128;

  const int srow = tid >> 2;
  const int scol = (tid & 3) * 8;
  const ushort_t* gA = A + (size_t)(bm + srow) * K + scol;
  const ushort_t* gB = W + (size_t)(bn + srow) * K + scol;
  ushort_t* lA = a_lds + w * 512;
  ushort_t* lB = b_lds + w * 512;
  const size_t half = (size_t)64 * K;

  f32x4 acc[4][4] = {};

  for (int k0 = 0; k0 < K; k0 += 64) {
    // kk=0 half (k0..k0+31): rows 0-63 then 64-127
    load_lds16(gA,             lA);
    load_lds16(gA + half,      lA + 2048);
    load_lds16(gB,             lB);
    load_lds16(gB + half,      lB + 2048);
    // kk=1 half (k0+32..k0+63): explicit +32-elem pointers
    load_lds16(gA + 32,        lA + 4096);
    load_lds16(gA + 32 + half, lA + 6144);
    load_lds16(gB + 32,        lB + 4096);
    load_lds16(gB + 32 + half, lB + 6144);
    gA += 64; gB += 64;
    __syncthreads();
#pragma unroll
    for (int kk = 0; kk < 2; ++kk) {
      short8 af[4], bfr[4];
#pragma unroll
      for (int i = 0; i < 4; ++i) {
        af[i]  = *(const short8*)&a_lds[kk * 4096 + (wr * 64 + i * 16 + l15) * 32 + quad * 8];
        bfr[i] = *(const short8*)&b_lds[kk * 4096 + (wc * 64 + i * 16 + l15) * 32 + quad * 8];
      }
#pragma unroll
      for (int i = 0; i < 4; ++i)
#pragma unroll
        for (int j = 0; j < 4; ++j)
          acc[i][j] = __builtin_amdgcn_mfma_f32_16x16x32_bf16(af[i], bfr[j], acc[i][j], 0, 0, 0);
    }
    __syncthreads();
  }

  const size_t SZq = (size_t)MROWS * D_DIM;
#pragma unroll
  for (int i = 0; i < 4; ++i) {
    const long row0 = bm + wr * 64 + i * 16 + quad * 4;
#pragma unroll
    for (int j = 0; j < 4; ++j) {
      const long col = bn + wc * 64 + j * 16 + l15;
      if (EPI == 4) {
        if (col < 4096) {  // q or k, row-major stride D_DIM
          ushort_t* dst = (ushort_t*)Cv + (col < 2048 ? 0 : SZq);
          const long c = col & (D_DIM - 1);
#pragma unroll
          for (int r = 0; r < 4; ++r)
            dst[(size_t)(row0 + r) * D_DIM + c] = f2bf(acc[i][j][r]);
        } else {           // v^T per head: vt[((b*16+h)*128+d)*S + s]
          const long b = row0 >> 11;
          const long s0 = row0 & (S_LEN - 1);
          const long h = (col >> 7) & 15;
          const long d = col & (HDIM - 1);
          short4v ov;
#pragma unroll
          for (int r = 0; r < 4; ++r) ov[r] = (short)f2bf(acc[i][j][r]);
          *(short4v*)((ushort_t*)Cv + 2 * SZq + ((b * NHEAD + h) * HDIM + d) * S_LEN + s0) = ov;
        }
      } else {
#pragma unroll
        for (int r = 0; r < 4; ++r) {
          float v = acc[i][j][r];
          const size_t idx = (size_t)(row0 + r) * N + col;
          if (EPI == 1) {
            ((float*)Cv)[idx] = v + RES[idx];
          } else if (EPI == 2) {
            v = 0.5f * v * (1.0f + erff(v * 0.70710678118654752f));
            ((ushort_t*)Cv)[idx] = f2bf(v);
          }
        }
      }
    }
  }
}

// ---------------------------------------------------------------------------
// Causal flash attention. 4 waves/block, 64-row Q tile (16 rows/wave),
// 64-key K-tiles shared across waves, staged via global_load_lds (w=16).
// qt dispatch REVERSED so heavy diagonal blocks launch first.
// ---------------------------------------------------------------------------
__global__ __launch_bounds__(256) void attn_kernel(const ushort_t* __restrict__ q,
                                                   const ushort_t* __restrict__ k,
                                                   const ushort_t* __restrict__ vt,
                                                   ushort_t* __restrict__ out) {
  __shared__ __align__(16) ushort_t K_lds[64 * 128];
  __shared__ __align__(16) ushort_t Vt_lds[128 * 64];
  __shared__ __align__(16) ushort_t P_lds[4 * 16 * 64];
  const int tid = threadIdx.x;
  const int w = tid >> 6;
  const int lane = tid & 63;
  const int quad = lane >> 4;
  const int l15 = lane & 15;

  const int qt = (S_LEN / 64 - 1) - (blockIdx.x & (S_LEN / 64 - 1));  // reversed
  const int bh = blockIdx.x >> 5;
  const int b = bh >> 4;
  const int h = bh & 15;
  const int q0 = qt * 64;
  const int wrow0 = q0 + w * 16;
  const size_t base = ((size_t)b * S_LEN) * D_DIM + h * HDIM;
  const size_t vtbase = ((size_t)(b * NHEAD + h)) * HDIM * S_LEN;

  short8 qa[4];
#pragma unroll
  for (int st = 0; st < 4; ++st)
    qa[st] = *(const short8*)(q + base + (size_t)(wrow0 + l15) * D_DIM + st * 32 + quad * 8);

  const int kc0 = w * 64 + lane;
  ushort_t* Pw = P_lds + w * 1024;

  f32x4 o[8] = {};
  float m[4], l[4];
#pragma unroll
  for (int r = 0; r < 4; ++r) { m[r] = -__builtin_inff(); l[r] = 0.f; }

  const int ktmax = (q0 + 63) >> 6;
  for (int kt = 0; kt <= ktmax; ++kt) {
#pragma unroll
    for (int r2 = 0; r2 < 4; ++r2) {
      const int c = r2 * 256 + kc0;
      {
        const int db = c >> 8, key = (c >> 2) & 63, dl = (c & 3) * 8;
        load_lds16(k + base + (size_t)(kt * 64 + key) * D_DIM + db * 32 + dl,
                   K_lds + (size_t)(r2 * 4 + w) * 512);
      }
      {
        const int kc = c >> 9, d = (c >> 2) & 127, kl = (c & 3) * 8;
        load_lds16(vt + vtbase + (size_t)d * S_LEN + kt * 64 + kc * 32 + kl,
                   Vt_lds + (size_t)(r2 * 4 + w) * 512);
      }
    }
    __syncthreads();

    if (kt * 64 <= wrow0 + 15) {
      f32x4 s[4];
#pragma unroll
      for (int h2 = 0; h2 < 4; ++h2) {
        f32x4 sa = {};
#pragma unroll
        for (int st = 0; st < 4; ++st) {
          short8 kb = *(const short8*)&K_lds[st * 2048 + (h2 * 16 + l15) * 32 + quad * 8];
          sa = __builtin_amdgcn_mfma_f32_16x16x32_bf16(qa[st], kb, sa, 0, 0, 0);
        }
        s[h2] = sa;
      }

      const int kbase = kt * 64 + l15;
      float alpha[4];
#pragma unroll
      for (int r = 0; r < 4; ++r) {
        const int qrow = wrow0 + quad * 4 + r;
        float sv[4];
#pragma unroll
        for (int h2 = 0; h2 < 4; ++h2)
          sv[h2] = (kbase + h2 * 16 <= qrow) ? s[h2][r] : -__builtin_inff();
        float tmax = fmaxf(fmaxf(sv[0], sv[1]), fmaxf(sv[2], sv[3]));
#pragma unroll
        for (int off = 8; off >= 1; off >>= 1) tmax = fmaxf(tmax, __shfl_xor(tmax, off));
        const float mn = fmaxf(m[r], tmax);
        const float al = __expf(m[r] - mn);
        float p[4], ps = 0.f;
#pragma unroll
        for (int h2 = 0; h2 < 4; ++h2) { p[h2] = __expf(sv[h2] - mn); ps += p[h2]; }
#pragma unroll
        for (int off = 8; off >= 1; off >>= 1) ps += __shfl_xor(ps, off);
        l[r] = l[r] * al + ps;
        m[r] = mn;
        alpha[r] = al;
#pragma unroll
        for (int h2 = 0; h2 < 4; ++h2)
          Pw[(h2 >> 1) * 512 + (quad * 4 + r) * 32 + (h2 & 1) * 16 + l15] = f2bf(p[h2]);
      }

#pragma unroll
      for (int c = 0; c < 8; ++c)
#pragma unroll
        for (int r = 0; r < 4; ++r) o[c][r] *= alpha[r];

      short8 af0 = *(const short8*)&Pw[l15 * 32 + quad * 8];
      short8 af1 = *(const short8*)&Pw[512 + l15 * 32 + quad * 8];
#pragma unroll
      for (int c = 0; c < 8; ++c) {
        short8 vb0 = *(const short8*)&Vt_lds[(c * 16 + l15) * 32 + quad * 8];
        o[c] = __builtin_amdgcn_mfma_f32_16x16x32_bf16(af0, vb0, o[c], 0, 0, 0);
        short8 vb1 = *(const short8*)&Vt_lds[4096 + (c * 16 + l15) * 32 + quad * 8];
        o[c] = __builtin_amdgcn_mfma_f32_16x16x32_bf16(af1, vb1, o[c], 0, 0, 0);
      }
    }
    __syncthreads();
  }

#pragma unroll
  for (int c = 0; c < 8; ++c)
#pragma unroll
    for (int r = 0; r < 4; ++r) {
      const float val = o[c][r] / l[r];
      out[base + (size_t)(wrow0 + quad * 4 + r) * D_DIM + c * 16 + l15] = f2bf(val);
    }
}

// ---------------------------------------------------------------------------
extern "C" void kernel_launch(void* const* d_in, const int* in_sizes, int n_in,
                              void* d_out, int out_size, void* d_ws, size_t ws_size,
                              hipStream_t stream) {
  const float* hid  = (const float*)d_in[0];
  const float* Wq   = (const float*)d_in[1];
  const float* Wk   = (const float*)d_in[2];
  const float* Wv   = (const float*)d_in[3];
  const float* Wo   = (const float*)d_in[4];
  const float* Win  = (const float*)d_in[5];
  const float* Wout = (const float*)d_in[6];
  // d_in[7] = qk_norm_factor == 1/sqrt(128), folded in as exact constant.
  const float* ga   = (const float*)d_in[8];
  const float* gm   = (const float*)d_in[9];
  float* out = (float*)d_out;

  const size_t DD = (size_t)D_DIM * D_DIM;
  const size_t FD = (size_t)F_DIM * D_DIM;
  const size_t SZ = (size_t)MROWS * D_DIM;

  ushort_t* wqb  = (ushort_t*)d_ws;     // wq|wk|wv contiguous = stacked [6144,2048]
  ushort_t* wob  = wqb + 3 * DD;
  ushort_t* winb = wob + DD;
  ushort_t* woutb= winb + FD;
  float*    hb   = (float*)(woutb + FD);      // h (fp32)
  ushort_t* qb   = (ushort_t*)(hb + SZ);      // q, later y_norm
  ushort_t* kb   = qb + SZ;                   // k      (qb+SZ: EPI4 contract)
  ushort_t* vtb  = kb + SZ;                   // v^T per head (qb+2SZ)
  ushort_t* xb   = vtb + SZ;                  // x_norm, later attn-out
  ushort_t* mid  = kb;                        // 67MB, overlays kb|vtb|xb + tail

  // one merged weight conversion (outputs contiguous at wqb)
  f2b_all_kernel<<<(unsigned)((4 * DD + 2 * FD) / 1024), 256, 0, stream>>>(
      Wq, Wk, Wv, Wo, Win, Wout, wqb);

  hsnorm_kernel<<<MROWS, 256, 0, stream>>>(hid, ga, xb);
  // fused QKV: A=xb, W=[Wq;Wk;Wv] stacked, routed epilogue
  gemm_bt<4><<<dim3(MROWS / 128, 6144 / 128), 256, 0, stream>>>(
      xb, wqb, nullptr, qb, MROWS, 6144, D_DIM);
  qknorm_kernel<<<(MROWS * NHEAD) / 4, 256, 0, stream>>>(qb, 0.08838834764831845f);
  qknorm_kernel<<<(MROWS * NHEAD) / 4, 256, 0, stream>>>(kb, 1.0f);
  attn_kernel<<<BATCH * NHEAD * (S_LEN / 64), 256, 0, stream>>>(qb, kb, vtb, xb);
  gemm_bt<1><<<dim3(MROWS / 128, D_DIM / 128), 256, 0, stream>>>(
      xb, wob, hid, hb, MROWS, D_DIM, D_DIM);
  hsnorm_kernel<<<MROWS, 256, 0, stream>>>(hb, gm, qb);
  gemm_bt<2><<<dim3(MROWS / 128, F_DIM / 128), 256, 0, stream>>>(
      qb, winb, nullptr, mid, MROWS, F_DIM, D_DIM);
  gemm_bt<1><<<dim3(MROWS / 128, D_DIM / 128), 256, 0, stream>>>(
      mid, woutb, hb, out, MROWS, D_DIM, F_DIM);
}